// Round 10
// baseline (291.959 us; speedup 1.0000x reference)
//
#include <hip/hip_runtime.h>
#include <math.h>

#define NTHREADS 512
#define TOUT 252
#define NDIF 264
#define NUU 266

// element strides (u16)
#define X1S 24              // x1: cols 0..19 data, 20 = 1.0 (bias col), 21..23 = 0
#define X2S 40              // x2 / x4 share this buffer+stride
#define T3S 32              // rolling 32-channel t3 buffer; col16 = 1.0 (bias col, phase 2)
#define X5S 24

// smem layout (bytes), all 16B aligned
#define SUU_OFF  0          // float[266]                         = 1064
#define X1_OFF   1072       // u16 x1 261x24 = 12528 ; x5 256x24 overlays
#define T3_OFF   13600      // u16 t3 256x32 = 16384 ; s_dif float[264] overlays
#define BUFB_OFF 29984      // u16 x2/x4 258x40 = 20640 ; beta float[254] overlays
#define SMEM_SIZE 50624

// weight-fragment table in d_ws: 42 frags x 64 lanes x 8 bf16 (16 B)
#define F2_BASE 0           // conv2: 15 frags (mt 0..2, s 0..4); bias b2 at s=2,ic=20
#define F3_BASE 15          // conv3: 10 frags (mt 0..4, s 0..1)
#define F4_BASE 25          // conv4: 9  frags (mt 0..2, s 0..2); bias b4 at s=2,k=80
#define F5_BASE 34          // conv5: 8  frags (mt 0..1, s 0..3)
#define NFRAGS 42

typedef unsigned short u16;
typedef unsigned int u32;
typedef __attribute__((ext_vector_type(8))) short bf16x8;
typedef __attribute__((ext_vector_type(4))) float f32x4;

// compiler-only memory fence: forbids reordering LDS writes/reads across the
// fused-phase hand-offs (DS pipe is in-order per wave, so HW side is safe).
#define MEM_FENCE() __asm__ __volatile__("" ::: "memory")

__device__ __forceinline__ float elu_f(float x) {
    return x > 0.0f ? x : (__expf(x) - 1.0f);
}
__device__ __forceinline__ float sq_f(float x) { return x * x; }
__device__ __forceinline__ u16 f2bf(float f) {              // RNE (setup kernel only)
    union { float f; u32 u; } v; v.f = f;
    u32 r = v.u + 0x7FFFu + ((v.u >> 16) & 1u);
    return (u16)(r >> 16);
}
__device__ __forceinline__ float bf2f(u16 h) {
    union { u32 u; float f; } v; v.u = ((u32)h) << 16;
    return v.f;
}
__device__ __forceinline__ u32 pack_trunc(float a, float b) {
    union { float f; u32 u; } va, vb; va.f = a; vb.f = b;
#if __has_builtin(__builtin_amdgcn_perm)
    return __builtin_amdgcn_perm(vb.u, va.u, 0x07060302u);
#else
    return (vb.u & 0xFFFF0000u) | (va.u >> 16);
#endif
}

// ---- setup kernel: build all MFMA A-operand weight frags once per launch ----
__global__ __launch_bounds__(64) void build_frags_kernel(
    const float* __restrict__ w2, const float* __restrict__ b2,
    const float* __restrict__ w3,
    const float* __restrict__ w4, const float* __restrict__ b4,
    const float* __restrict__ w5,
    u16* __restrict__ ws)
{
    const int f = blockIdx.x;      // 0..41
    const int lane = threadIdx.x;  // 0..63
    const int m = lane & 15;
    const int q = lane >> 4;
    float wvv[8];
    #pragma unroll
    for (int j = 0; j < 8; ++j) wvv[j] = 0.0f;

    if (f < F3_BASE) {                       // conv2: 20->40 k=5, K = dk*32+ic
        int mt = (f - F2_BASE) / 5, s = (f - F2_BASE) % 5;
        int oc = mt * 16 + m;
        #pragma unroll
        for (int j = 0; j < 8; ++j) {
            int ic = q * 8 + j;
            if (oc < 40 && ic < 20) wvv[j] = w2[oc * 100 + ic * 5 + s];
        }
        if (s == 2 && q == 2 && oc < 40) wvv[4] = b2[oc];   // bias at ic=20 (B=1.0)
    } else if (f < F4_BASE) {                // conv3: 40->80 k=1, K=40 pad 64
        int mt = (f - F3_BASE) / 2, s = (f - F3_BASE) % 2;
        int oc = mt * 16 + m;
        #pragma unroll
        for (int j = 0; j < 8; ++j) {
            int k = s * 32 + q * 8 + j;
            if (k < 40) wvv[j] = w3[oc * 40 + k];
        }
    } else if (f < F5_BASE) {                // conv4: 80->40 k=1, K=80 pad 96
        int mt = (f - F4_BASE) / 3, s = (f - F4_BASE) % 3;
        int oc = mt * 16 + m;
        #pragma unroll
        for (int j = 0; j < 8; ++j) {
            int k = s * 32 + q * 8 + j;
            if (oc < 40 && k < 80) wvv[j] = w4[oc * 80 + k];
        }
        if (s == 2 && q == 2 && oc < 40) wvv[0] = b4[oc];   // bias at k=80 (t3 col16=1.0)
    } else {                                 // conv5: 40->20 k=3, K=120: k=dk*40+ic
        int mt = (f - F5_BASE) / 4, s = (f - F5_BASE) % 4;
        int oc = mt * 16 + m;
        int k0 = s * 32 + q * 8;
        int dk = k0 / 40, ic0 = k0 - dk * 40;
        #pragma unroll
        for (int j = 0; j < 8; ++j) {
            if (oc < 20 && k0 < 120) wvv[j] = w5[oc * 120 + (ic0 + j) * 3 + dk];
        }
    }
    u32 pk[4];
    #pragma unroll
    for (int p = 0; p < 4; ++p)
        pk[p] = (u32)f2bf(wvv[2 * p]) | ((u32)f2bf(wvv[2 * p + 1]) << 16);
    u32* wp = (u32*)&ws[(f * 64 + lane) * 8];
    wp[0] = pk[0]; wp[1] = pk[1]; wp[2] = pk[2]; wp[3] = pk[3];
}

__device__ __forceinline__ bf16x8 ld_frag(const u16* ws, int f, int lane) {
    return *(const bf16x8*)&ws[(f * 64 + lane) * 8];
}

// (512,6): target 3 blocks/CU (LDS 49.4KB); VGPR cap ~85, per-phase design ~70.
__global__ __launch_bounds__(NTHREADS, 6) void weno_nn_kernel(
    const float* __restrict__ uu, const float* __restrict__ e_ptr,
    const float* __restrict__ w1, const float* __restrict__ b1,
    const float* __restrict__ b3, const float* __restrict__ b5,
    const float* __restrict__ w6, const float* __restrict__ b6,
    const u16* __restrict__ wfr,
    float* __restrict__ out, int n_out, int N)
{
    __shared__ __align__(16) unsigned char smem[SMEM_SIZE];
    float* s_uu  = (float*)(smem + SUU_OFF);
    float* s_dif = (float*)(smem + T3_OFF);      // overlays t3 (dead before t3 lives)
    u16*   x1    = (u16*)(smem + X1_OFF);
    u16*   x5    = (u16*)(smem + X1_OFF);        // overlays x1 (x1 dead after conv2)
    u16*   t3    = (u16*)(smem + T3_OFF);
    u16*   xB    = (u16*)(smem + BUFB_OFF);      // x2, later x4 (own-row overwrite)
    float* beta  = (float*)(smem + BUFB_OFF);    // overlays x2/x4 (dead after conv5)

    const int tid  = threadIdx.x;
    const int lane = tid & 63;
    const int wv   = __builtin_amdgcn_readfirstlane(tid >> 6);   // 0..7
    const int m    = lane & 15;
    const int q    = lane >> 4;
    const int J0   = blockIdx.x * TOUT;
    const int P0   = J0 + 2;
    const int U0   = J0 - 4;

    // ---------- stage 0: uu tile ----------
    for (int i = tid; i < NUU; i += NTHREADS) {
        int g = U0 + i;
        s_uu[i] = (g >= 0 && g < N) ? uu[g] : 0.0f;
    }
    __syncthreads();

    // ---------- avg-diff ----------
    for (int d = tid; d < NDIF; d += NTHREADS) {
        int g = P0 - 5 + d;
        float v = 0.0f;
        if (g >= 0 && g < N) {
            int j1 = g < N - 2 ? g : N - 2;
            int j0 = g - 1 > 0 ? g - 1 : 0;
            float dl = s_uu[j1 + 1 - U0] - s_uu[j1 - U0];
            float dr = s_uu[j0 + 1 - U0] - s_uu[j0 - U0];
            v = 0.5f * (dl + dr);
        }
        s_dif[d] = v;
    }
    __syncthreads();

    // ---------- conv1 (VALU): 1->20, k=5, elu -> x1[row][ic], bias col20 = 1.0 ----------
    // zero x4 rows 256,257 (conv5 right edge) and x1 row 260 (conv2 q=3 wrap-read target)
    if (tid < 40) ((u32*)&xB[256 * X2S])[tid] = 0;
    if (tid >= 64 && tid < 76) ((u32*)&x1[260 * X1S])[tid - 64] = 0;
    for (int s = tid; s < 260; s += NTHREADS) {
        int g = P0 - 3 + s;
        bool valid = (g >= 0 && g < N);
        float dv[5];
        #pragma unroll
        for (int k = 0; k < 5; ++k) dv[k] = s_dif[s + k];
        float v[20];
        #pragma unroll
        for (int oc = 0; oc < 20; ++oc) {
            float a = b1[oc];
            #pragma unroll
            for (int k = 0; k < 5; ++k) a += w1[oc * 5 + k] * dv[k];
            v[oc] = valid ? elu_f(a) : 0.0f;
        }
        u32* rp = (u32*)&x1[s * X1S];
        #pragma unroll
        for (int p = 0; p < 10; ++p)
            rp[p] = pack_trunc(v[2 * p], v[2 * p + 1]);
        rp[10] = valid ? 0x00003F80u : 0u;   // col20 = bf16(1.0), col21 = 0
        rp[11] = 0u;
    }
    __syncthreads();

    // ---------- fused conv2 -> conv3 -> conv4 (k=1 column-local, same-wave rows) ----------
    for (int t = 0; t < 2; ++t) {
        const int row = (wv * 2 + t) * 16 + m;      // this lane's position row

        // conv2: 20->40 k=5 (im2col K=160), bias via frag s=2 x col20
        bf16x8 Bx1[5];
        #pragma unroll
        for (int s = 0; s < 5; ++s)
            Bx1[s] = *(const bf16x8*)&x1[(row + s) * X1S + q * 8];
        #pragma unroll
        for (int mt2 = 0; mt2 < 3; ++mt2) {
            f32x4 acc = {0.f, 0.f, 0.f, 0.f};
            #pragma unroll
            for (int s = 0; s < 5; ++s)
                acc = __builtin_amdgcn_mfma_f32_16x16x32_bf16(
                    ld_frag(wfr, F2_BASE + mt2 * 5 + s, lane), Bx1[s], acc, 0, 0, 0);
            int oc0 = mt2 * 16 + 4 * q;
            if (oc0 < 40) {
                u32* wp = (u32*)&xB[row * X2S + oc0];
                wp[0] = pack_trunc(elu_f(acc[0]), elu_f(acc[1]));
                wp[1] = pack_trunc(elu_f(acc[2]), elu_f(acc[3]));
            }
        }
        MEM_FENCE();   // conv2 writes (u32) -> conv3 reads (bf16x8), same-wave rows

        // conv3+conv4 K-phased through 32-ch rolling t3 (same-wave rows only)
        bf16x8 Bx2a = *(const bf16x8*)&xB[row * X2S + q * 8];                 // k 0..31
        bf16x8 Bx2b = *(const bf16x8*)&xB[row * X2S + ((q == 0) ? 32 : 0)];   // k 32..39; q!=0: zero-wt
        f32x4 acc4[3];
        #pragma unroll
        for (int mt4 = 0; mt4 < 3; ++mt4)
            acc4[mt4] = (f32x4){0.f, 0.f, 0.f, 0.f};
        #pragma unroll
        for (int p3 = 0; p3 < 3; ++p3) {
            const int nmt = (p3 < 2) ? 2 : 1;
            #pragma unroll
            for (int i = 0; i < nmt; ++i) {
                int mt = 2 * p3 + i;
                f32x4 a3 = *(const f32x4*)&b3[16 * mt + 4 * q];        // f32 bias seed
                a3 = __builtin_amdgcn_mfma_f32_16x16x32_bf16(
                    ld_frag(wfr, F3_BASE + mt * 2 + 0, lane), Bx2a, a3, 0, 0, 0);
                a3 = __builtin_amdgcn_mfma_f32_16x16x32_bf16(
                    ld_frag(wfr, F3_BASE + mt * 2 + 1, lane), Bx2b, a3, 0, 0, 0);
                u32* wp = (u32*)&t3[row * T3S + 16 * i + 4 * q];
                wp[0] = pack_trunc(elu_f(a3[0]), elu_f(a3[1]));
                wp[1] = pack_trunc(elu_f(a3[2]), elu_f(a3[3]));
            }
            if (p3 == 2 && q == 0)
                *(u32*)&t3[row * T3S + 16] = 0x00003F80u;   // t3 col16 = 1.0 (bias B for k=80)
            MEM_FENCE();   // conv3/bias writes -> conv4 Bt read, same-wave rows
            bf16x8 Bt = *(const bf16x8*)&t3[row * T3S + q * 8];
            #pragma unroll
            for (int mt4 = 0; mt4 < 3; ++mt4)
                acc4[mt4] = __builtin_amdgcn_mfma_f32_16x16x32_bf16(
                    ld_frag(wfr, F4_BASE + mt4 * 3 + p3, lane), Bt, acc4[mt4], 0, 0, 0);
            MEM_FENCE();   // Bt read before next phase overwrites t3
        }
        // conv4 epilogue -> x4 (overwrites x2 in own rows only)
        #pragma unroll
        for (int mt4 = 0; mt4 < 3; ++mt4) {
            int oc0 = mt4 * 16 + 4 * q;
            if (oc0 < 40) {
                u32* wp = (u32*)&xB[row * X2S + oc0];
                wp[0] = pack_trunc(elu_f(acc4[mt4][0]), elu_f(acc4[mt4][1]));
                wp[1] = pack_trunc(elu_f(acc4[mt4][2]), elu_f(acc4[mt4][3]));
            }
        }
        MEM_FENCE();
    }
    __syncthreads();

    // ---------- conv5: 40->20 k=3 (im2col K=120), f32 bias seed ----------
    for (int t = 0; t < 2; ++t) {
        const int row = (wv * 2 + t) * 16 + m;
        bf16x8 B5[4];
        #pragma unroll
        for (int s = 0; s < 4; ++s) {
            int k0 = 32 * s + 8 * q;
            int dk, ic0;
            if (k0 < 120) {
                dk = (k0 >= 80) ? 2 : ((k0 >= 40) ? 1 : 0);
                ic0 = k0 - 40 * dk;
            } else { dk = 0; ic0 = 0; }              // valid x4 data x zero-A
            B5[s] = *(const bf16x8*)&xB[(row + dk) * X2S + ic0];
        }
        #pragma unroll
        for (int mt5 = 0; mt5 < 2; ++mt5) {
            int bo = (mt5 == 0) ? 4 * q : 16;        // clamped seed addr (oc>=20 unused)
            f32x4 acc = *(const f32x4*)&b5[bo];
            #pragma unroll
            for (int s = 0; s < 4; ++s)
                acc = __builtin_amdgcn_mfma_f32_16x16x32_bf16(
                    ld_frag(wfr, F5_BASE + mt5 * 4 + s, lane), B5[s], acc, 0, 0, 0);
            int oc0 = mt5 * 16 + 4 * q;
            if (oc0 < 20) {
                u32* wp = (u32*)&x5[row * X5S + oc0];
                wp[0] = pack_trunc(elu_f(acc[0]), elu_f(acc[1]));
                wp[1] = pack_trunc(elu_f(acc[2]), elu_f(acc[3]));
            }
        }
    }
    __syncthreads();

    // ---------- conv6: 20->1, sigmoid + 0.1 -> beta ----------
    if (tid < 254) {
        float a = b6[0];
        #pragma unroll
        for (int c = 0; c < 20; ++c)
            a += w6[c] * bf2f(x5[tid * X5S + c]);
        beta[tid] = 1.0f / (1.0f + __expf(-a)) + 0.1f;
    }
    __syncthreads();

    // ---------- WENO5 ----------
    const float eps = e_ptr[0];
    if (tid < TOUT) {
        int j = J0 + tid;
        if (j < n_out) {
            float a  = s_uu[tid + 5];
            float b  = s_uu[tid + 6];
            float c  = s_uu[tid + 7];
            float d  = s_uu[tid + 8];
            float ee = s_uu[tid + 9];
            float f  = s_uu[tid + 10];
            float m0 = beta[tid];
            float m1 = beta[tid + 1];
            float m2 = beta[tid + 2];

            const float i6 = 1.0f / 6.0f;
            float fp0 = (11.f * d - 7.f * ee + 2.f * f) * i6;
            float fp1 = (2.f * c + 5.f * d - ee) * i6;
            float fp2 = (-b + 5.f * c + 2.f * d) * i6;
            float fn0 = (11.f * c - 7.f * d + 2.f * ee) * i6;
            float fn1 = (2.f * b + 5.f * c - d) * i6;
            float fn2 = (-a + 5.f * b + 2.f * c) * i6;

            const float c1312 = 13.f / 12.f;
            float bp0 = c1312 * sq_f(d - 2.f * ee + f) + 0.25f * sq_f(3.f * d - 4.f * ee + f);
            float bp1 = c1312 * sq_f(c - 2.f * d + ee) + 0.25f * sq_f(c - ee);
            float bp2 = c1312 * sq_f(b - 2.f * c + d) + 0.25f * sq_f(b - 4.f * c + 3.f * d);
            float bn0 = c1312 * sq_f(c - 2.f * d + ee) + 0.25f * sq_f(3.f * c - 4.f * d + ee);
            float bn1 = c1312 * sq_f(b - 2.f * c + d) + 0.25f * sq_f(b - d);
            float bn2 = c1312 * sq_f(a - 2.f * b + c) + 0.25f * sq_f(a - 4.f * b + 3.f * c);

            bp0 *= m0; bp1 *= m1; bp2 *= m2;
            bn0 *= m0; bn1 *= m1; bn2 *= m2;

            float q0 = eps + bp0; q0 *= q0;
            float q1 = eps + bp1; q1 *= q1;
            float q2 = eps + bp2; q2 *= q2;
            float brs = bp2 - bp0; brs *= brs;
            float o0 = 0.1f * (1.f + brs / q0);
            float o1 = 0.6f * (1.f + brs / q1);
            float o2 = 0.3f * (1.f + brs / q2);
            float inv = 1.f / (o0 + o1 + o2);
            float fluxp = (o0 * fp0 + o1 * fp1 + o2 * fp2) * inv;

            q0 = eps + bn0; q0 *= q0;
            q1 = eps + bn1; q1 *= q1;
            q2 = eps + bn2; q2 *= q2;
            brs = bn2 - bn0; brs *= brs;
            o0 = 0.1f * (1.f + brs / q0);
            o1 = 0.6f * (1.f + brs / q1);
            o2 = 0.3f * (1.f + brs / q2);
            inv = 1.f / (o0 + o1 + o2);
            float fluxn = (o0 * fn0 + o1 * fn1 + o2 * fn2) * inv;

            out[j] = fluxp - fluxn;
        }
    }
}

extern "C" void kernel_launch(void* const* d_in, const int* in_sizes, int n_in,
                              void* d_out, int out_size, void* d_ws, size_t ws_size,
                              hipStream_t stream) {
    const float* uu = (const float*)d_in[0];
    const float* e  = (const float*)d_in[1];
    const float* w1 = (const float*)d_in[2];
    const float* b1 = (const float*)d_in[3];
    const float* w2 = (const float*)d_in[4];
    const float* b2 = (const float*)d_in[5];
    const float* w3 = (const float*)d_in[6];
    const float* b3 = (const float*)d_in[7];
    const float* w4 = (const float*)d_in[8];
    const float* b4 = (const float*)d_in[9];
    const float* w5 = (const float*)d_in[10];
    const float* b5 = (const float*)d_in[11];
    const float* w6 = (const float*)d_in[12];
    const float* b6 = (const float*)d_in[13];
    float* out = (float*)d_out;
    u16* wfr = (u16*)d_ws;
    const int N = in_sizes[0];
    const int nblocks = (out_size + TOUT - 1) / TOUT;

    build_frags_kernel<<<NFRAGS, 64, 0, stream>>>(w2, b2, w3, w4, b4, w5, wfr);
    weno_nn_kernel<<<nblocks, NTHREADS, 0, stream>>>(
        uu, e, w1, b1, b3, b5, w6, b6, wfr,
        out, out_size, N);
}